// Round 8
// baseline (14.066 us; speedup 1.0000x reference)
//
#include <hip/hip_runtime.h>

#define RES_V 16
#define RES_H 32
#define NS    100
#define GRD   256
#define NCH   11
#define BLK   256           // 16 sample-groups x 2 channel-halves x 8 corners
#define CHUNK 16
#define SPECN 12            // speculate full channels for samples 0..11 only
#define EPS   1e-5f         // dead-sample threshold

__device__ __forceinline__ int iclamp(int x, int lo, int hi) {
    return x < lo ? lo : (x > hi ? hi : x);
}

// One block per ray, 4 waves, 256 threads.
// tid = sg*16 + h*8 + corner:  sg = sample-in-chunk 0..15, h = channel-half,
// corner bits: cx=bit0, cy=bit1, cz=bit2.
// Half A (h=0): {3,0,1,2,4} (alpha first), half B (h=1): {5..10}.
// Chunk 0: full-channel speculation for samples 0..SPECN-1, alpha-only for
// SPECN..15 (h=0 lanes). Live-but-unspeculated samples go through the
// fallback gather (rare: ~31% of rays, 1-2 samples each). Later chunks:
// alpha-only + fallback, guarded by block-uniform running_T (rare: ~13%).
__global__ __launch_bounds__(BLK) void sglv_render_kernel(
    const float* __restrict__ origin,
    const float* __restrict__ SGLV,
    const float* __restrict__ vrange,
    float* __restrict__ out)
{
    const int ray    = blockIdx.x;      // 0..511
    const int v      = ray >> 5;
    const int u      = ray & 31;
    const int tid    = threadIdx.x;     // 0..255
    const int lane   = tid & 63;
    const int wid    = tid >> 6;        // 0..3
    const int corner = tid & 7;
    const int h      = (tid >> 3) & 1;
    const int sg     = tid >> 4;        // 0..15

    __shared__ float s_wtot[4];         // per-wave chunk transmittance factor
    __shared__ float s_red[4][NCH];     // per-wave channel partial sums

    const int chA[5] = {3, 0, 1, 2, 4};
    const int chB[6] = {5, 6, 7, 8, 9, 10};

    // ---- direction (f32 trig; validated rounds 2-7) ----
    const float PIF = 3.14159265358979323846f;
    float phi   = (2.0f * PIF / (float)RES_H) * (float)u;
    float theta = (PIF / (float)RES_V) * (float)v;
    float stv = sinf(theta);
    float dx0 = stv * cosf(phi);
    float dy0 = cosf(theta);
    float dz0 = stv * sinf(phi);
    float nrm = sqrtf(dx0 * dx0 + dy0 * dy0 + dz0 * dz0);
    nrm = fmaxf(nrm, 1e-12f);
    float d[3] = { dx0 / nrm, dy0 / nrm, dz0 / nrm };

    float org[3] = { origin[0], origin[1], origin[2] };
    float vr0[3] = { vrange[0], vrange[1], vrange[2] };
    float vr1[3] = { vrange[3], vrange[4], vrange[5] };

    // ---- ray-box (reference slab logic incl. strict >0 and +-inf) ----
    const float INF = __builtin_inff();
    float t0 = INF, t1 = INF;
    #pragma unroll
    for (int k = 0; k < 3; ++k) {
        float num0 = vr0[k] - org[k];
        float num1 = vr1[k] - org[k];
        float tmin, tmax;
        if (d[k] == 0.0f) {
            tmin = (num0 > 0.0f) ? INF : -INF;
            tmax = (num1 > 0.0f) ? INF : -INF;
        } else {
            tmin = num0 / d[k];
            tmax = num1 / d[k];
        }
        t0 = fminf(t0, (tmin > 0.0f) ? tmin : INF);
        t1 = fminf(t1, (tmax > 0.0f) ? tmax : INF);
    }
    float t_end   = fminf(t0, t1);
    float t_start = 0.0f;

    // grid-space ray: idx_k(t) = (org+t*d - vr0) * scale_k
    float scale[3], gorg[3], gdir[3];
    #pragma unroll
    for (int k = 0; k < 3; ++k) {
        scale[k] = (float)(GRD - 1) / (vr1[k] - vr0[k]);
        gorg[k]  = (org[k] - vr0[k]) * scale[k];
        gdir[k]  = d[k] * scale[k];
    }
    const float dt = (t_end - t_start) * (1.0f / (float)(NS - 1));

    const size_t CS = (size_t)GRD * GRD * GRD;

    float accL[6];
    #pragma unroll
    for (int i = 0; i < 6; ++i) accL[i] = 0.0f;
    float running_T = 1.0f;             // block-uniform

    for (int s0 = 0; s0 < NS; s0 += CHUNK) {
        const int  s   = s0 + sg;
        const bool act = (s < NS);

        // ---- address + trilerp weight ----
        float  w = 0.0f;
        size_t base = 0;
        if (act) {
            float t = t_start + (float)s * dt;
            float ix = gorg[0] + t * gdir[0];
            float iy = gorg[1] + t * gdir[1];
            float iz = gorg[2] + t * gdir[2];
            float x0f = floorf(ix), y0f = floorf(iy), z0f = floorf(iz);
            float fx = ix - x0f, fy = iy - y0f, fz = iz - z0f;
            int x0 = (int)x0f, y0 = (int)y0f, z0 = (int)z0f;
            int cx = corner & 1, cy = (corner >> 1) & 1, cz = corner >> 2;
            int xi = x0 + cx, yi = y0 + cy, zi = z0 + cz;
            w = (cx ? fx : 1.0f - fx)
              * (cy ? fy : 1.0f - fy)
              * (cz ? fz : 1.0f - fz);
            bool valid = ((unsigned)xi < GRD) & ((unsigned)yi < GRD)
                       & ((unsigned)zi < GRD);
            w = valid ? w : 0.0f;
            int xc = iclamp(xi, 0, GRD - 1);
            int yc = iclamp(yi, 0, GRD - 1);
            int zc = iclamp(zi, 0, GRD - 1);
            base = ((size_t)zc * GRD + (size_t)yc) * GRD + (size_t)xc;
        }

        // ---- load burst ----
        float part[6];
        #pragma unroll
        for (int i = 0; i < 6; ++i) part[i] = 0.0f;
        const bool spec = (s0 == 0) && (sg < SPECN);   // trimmed speculation
        if (act) {
            if (spec) {
                if (h == 0) {
                    #pragma unroll
                    for (int i = 0; i < 5; ++i)
                        part[i] = w * SGLV[(size_t)chA[i] * CS + base];
                } else {
                    #pragma unroll
                    for (int i = 0; i < 6; ++i)
                        part[i] = w * SGLV[(size_t)chB[i] * CS + base];
                }
            } else if (h == 0) {
                part[0] = w * SGLV[3 * CS + base];   // alpha only
            }
        }

        // ---- alpha: corner-reduce (h=0), broadcast to h=1 ----
        float alpha = part[0];
        alpha += __shfl_xor(alpha, 1, 64);
        alpha += __shfl_xor(alpha, 2, 64);
        alpha += __shfl_xor(alpha, 4, 64);
        float aswap = __shfl_xor(alpha, 8, 64);
        alpha = h ? aswap : alpha;              // 16-lane supergroup uniform

        // ---- cumprod scan: shfl_up 16,32 within wave + LDS cross-wave ----
        float fac = act ? (1.0f - alpha) + 1e-10f : 1.0f;
        float p = fac;
        {
            float o = __shfl_up(p, 16, 64); if (lane >= 16) p *= o;
            o       = __shfl_up(p, 32, 64); if (lane >= 32) p *= o;
        }
        if (lane == 63) s_wtot[wid] = p;
        __syncthreads();

        float pre = running_T;
        for (int w2 = 0; w2 < wid; ++w2) pre *= s_wtot[w2];
        float chunk_prod = s_wtot[0] * s_wtot[1] * s_wtot[2] * s_wtot[3];
        float T   = pre * p;                    // inclusive transmittance
        float wgt = act ? alpha * T : 0.0f;
        const bool live = act && (T > EPS);

        // ---- fallback: live non-spec samples gather their half ----
        if (live && !spec) {
            if (h == 0) {
                #pragma unroll
                for (int i = 1; i < 5; ++i)
                    part[i] = w * SGLV[(size_t)chA[i] * CS + base];
            } else {
                #pragma unroll
                for (int i = 0; i < 6; ++i)
                    part[i] = w * SGLV[(size_t)chB[i] * CS + base];
            }
        }

        // ---- accumulate (spec threads exact regardless of live) ----
        #pragma unroll
        for (int i = 0; i < 6; ++i)
            accL[i] += wgt * part[i];

        running_T *= chunk_prod;
        __syncthreads();                        // protect s_wtot next iter
        if (running_T <= EPS) break;            // block-uniform exit
    }

    // ---- masked butterfly: reduce over corner+sg bits, NOT the h bit ----
    #pragma unroll
    for (int i = 0; i < 6; ++i) {
        float val = accL[i];
        val += __shfl_xor(val, 1, 64);
        val += __shfl_xor(val, 2, 64);
        val += __shfl_xor(val, 4, 64);
        val += __shfl_xor(val, 16, 64);
        val += __shfl_xor(val, 32, 64);
        accL[i] = val;                          // lane 0 (h=0) / 8 (h=1)
    }
    if (lane == 0) {
        #pragma unroll
        for (int i = 0; i < 5; ++i) s_red[wid][chA[i]] = accL[i];
    }
    if (lane == 8) {
        #pragma unroll
        for (int i = 0; i < 6; ++i) s_red[wid][chB[i]] = accL[i];
    }
    __syncthreads();

    if (tid == 0) {
        float a[NCH];
        #pragma unroll
        for (int c = 0; c < NCH; ++c)
            a[c] = s_red[0][c] + s_red[1][c] + s_red[2][c] + s_red[3][c];
        float sdd = d[0] * a[8] + d[1] * a[9] + d[2] * a[10];
        float e = expf(a[7] * (sdd - 1.0f));
        int pix = v * RES_H + u;
        out[0 * RES_V * RES_H + pix] = a[0] + a[4] * e;
        out[1 * RES_V * RES_H + pix] = a[1] + a[5] * e;
        out[2 * RES_V * RES_H + pix] = a[2] + a[6] * e;
    }
}

extern "C" void kernel_launch(void* const* d_in, const int* in_sizes, int n_in,
                              void* d_out, int out_size, void* d_ws, size_t ws_size,
                              hipStream_t stream) {
    const float* origin = (const float*)d_in[0];
    const float* SGLV   = (const float*)d_in[1];
    const float* vrange = (const float*)d_in[2];
    float* out = (float*)d_out;

    sglv_render_kernel<<<dim3(RES_V * RES_H), dim3(BLK), 0, stream>>>(
        origin, SGLV, vrange, out);
}

// Round 9
// 12.164 us; speedup vs baseline: 1.1563x; 1.1563x over previous
//
#include <hip/hip_runtime.h>

#define RES_V 16
#define RES_H 32
#define NS    100
#define GRD   256
#define NCH   11
#define BLK   256           // 16 sample-groups x 2 channel-halves x 8 corners
#define CHUNK 16
#define EPS   1e-5f         // dead-sample threshold

__device__ __forceinline__ int iclamp(int x, int lo, int hi) {
    return x < lo ? lo : (x > hi ? hi : x);
}

// One block per ray, 4 waves, 256 threads. Identical to round-7 structure
// (best so far: full-channel speculation for the whole first 16-sample chunk,
// single memory round trip for ~87% of rays) plus an XCD-locality ray remap:
// blocks bid with bid%8==k dispatch to XCD k (round-robin), so giving XCD k
// the contiguous ray range [k*64,(k+1)*64) makes overlapping mid-range
// footprints land in the same (non-coherent) L2.
__global__ __launch_bounds__(BLK) void sglv_render_kernel(
    const float* __restrict__ origin,
    const float* __restrict__ SGLV,
    const float* __restrict__ vrange,
    float* __restrict__ out)
{
    const int bid    = blockIdx.x;
    const int ray    = (bid & 7) * 64 + (bid >> 3);   // XCD-contiguous patches
    const int v      = ray >> 5;
    const int u      = ray & 31;
    const int tid    = threadIdx.x;     // 0..255
    const int lane   = tid & 63;
    const int wid    = tid >> 6;        // 0..3
    const int corner = tid & 7;
    const int h      = (tid >> 3) & 1;
    const int sg     = tid >> 4;        // 0..15

    __shared__ float s_wtot[4];         // per-wave chunk transmittance factor
    __shared__ float s_red[4][NCH];     // per-wave channel partial sums

    const int chA[5] = {3, 0, 1, 2, 4};
    const int chB[6] = {5, 6, 7, 8, 9, 10};

    // ---- direction (f32 trig; validated rounds 2-8) ----
    const float PIF = 3.14159265358979323846f;
    float phi   = (2.0f * PIF / (float)RES_H) * (float)u;
    float theta = (PIF / (float)RES_V) * (float)v;
    float stv = sinf(theta);
    float dx0 = stv * cosf(phi);
    float dy0 = cosf(theta);
    float dz0 = stv * sinf(phi);
    float nrm = sqrtf(dx0 * dx0 + dy0 * dy0 + dz0 * dz0);
    nrm = fmaxf(nrm, 1e-12f);
    float d[3] = { dx0 / nrm, dy0 / nrm, dz0 / nrm };

    float org[3] = { origin[0], origin[1], origin[2] };
    float vr0[3] = { vrange[0], vrange[1], vrange[2] };
    float vr1[3] = { vrange[3], vrange[4], vrange[5] };

    // ---- ray-box (reference slab logic incl. strict >0 and +-inf) ----
    const float INF = __builtin_inff();
    float t0 = INF, t1 = INF;
    #pragma unroll
    for (int k = 0; k < 3; ++k) {
        float num0 = vr0[k] - org[k];
        float num1 = vr1[k] - org[k];
        float tmin, tmax;
        if (d[k] == 0.0f) {
            tmin = (num0 > 0.0f) ? INF : -INF;
            tmax = (num1 > 0.0f) ? INF : -INF;
        } else {
            tmin = num0 / d[k];
            tmax = num1 / d[k];
        }
        t0 = fminf(t0, (tmin > 0.0f) ? tmin : INF);
        t1 = fminf(t1, (tmax > 0.0f) ? tmax : INF);
    }
    float t_end   = fminf(t0, t1);
    float t_start = 0.0f;

    // grid-space ray: idx_k(t) = (org+t*d - vr0) * scale_k
    float scale[3], gorg[3], gdir[3];
    #pragma unroll
    for (int k = 0; k < 3; ++k) {
        scale[k] = (float)(GRD - 1) / (vr1[k] - vr0[k]);
        gorg[k]  = (org[k] - vr0[k]) * scale[k];
        gdir[k]  = d[k] * scale[k];
    }
    const float dt = (t_end - t_start) * (1.0f / (float)(NS - 1));

    const size_t CS = (size_t)GRD * GRD * GRD;

    float accL[6];
    #pragma unroll
    for (int i = 0; i < 6; ++i) accL[i] = 0.0f;
    float running_T = 1.0f;             // block-uniform

    for (int s0 = 0; s0 < NS; s0 += CHUNK) {
        const int  s   = s0 + sg;
        const bool act = (s < NS);

        // ---- address + trilerp weight ----
        float  w = 0.0f;
        size_t base = 0;
        if (act) {
            float t = t_start + (float)s * dt;
            float ix = gorg[0] + t * gdir[0];
            float iy = gorg[1] + t * gdir[1];
            float iz = gorg[2] + t * gdir[2];
            float x0f = floorf(ix), y0f = floorf(iy), z0f = floorf(iz);
            float fx = ix - x0f, fy = iy - y0f, fz = iz - z0f;
            int x0 = (int)x0f, y0 = (int)y0f, z0 = (int)z0f;
            int cx = corner & 1, cy = (corner >> 1) & 1, cz = corner >> 2;
            int xi = x0 + cx, yi = y0 + cy, zi = z0 + cz;
            w = (cx ? fx : 1.0f - fx)
              * (cy ? fy : 1.0f - fy)
              * (cz ? fz : 1.0f - fz);
            bool valid = ((unsigned)xi < GRD) & ((unsigned)yi < GRD)
                       & ((unsigned)zi < GRD);
            w = valid ? w : 0.0f;
            int xc = iclamp(xi, 0, GRD - 1);
            int yc = iclamp(yi, 0, GRD - 1);
            int zc = iclamp(zi, 0, GRD - 1);
            base = ((size_t)zc * GRD + (size_t)yc) * GRD + (size_t)xc;
        }

        // ---- load burst ----
        float part[6];
        #pragma unroll
        for (int i = 0; i < 6; ++i) part[i] = 0.0f;
        const bool spec = (s0 == 0);            // chunk 0: full speculation
        if (act) {
            if (spec) {
                if (h == 0) {
                    #pragma unroll
                    for (int i = 0; i < 5; ++i)
                        part[i] = w * SGLV[(size_t)chA[i] * CS + base];
                } else {
                    #pragma unroll
                    for (int i = 0; i < 6; ++i)
                        part[i] = w * SGLV[(size_t)chB[i] * CS + base];
                }
            } else if (h == 0) {
                part[0] = w * SGLV[3 * CS + base];   // alpha only
            }
        }

        // ---- alpha: corner-reduce (h=0), broadcast to h=1 ----
        float alpha = part[0];
        alpha += __shfl_xor(alpha, 1, 64);
        alpha += __shfl_xor(alpha, 2, 64);
        alpha += __shfl_xor(alpha, 4, 64);
        float aswap = __shfl_xor(alpha, 8, 64);
        alpha = h ? aswap : alpha;              // 16-lane supergroup uniform

        // ---- cumprod scan: shfl_up 16,32 within wave + LDS cross-wave ----
        float fac = act ? (1.0f - alpha) + 1e-10f : 1.0f;
        float p = fac;
        {
            float o = __shfl_up(p, 16, 64); if (lane >= 16) p *= o;
            o       = __shfl_up(p, 32, 64); if (lane >= 32) p *= o;
        }
        if (lane == 63) s_wtot[wid] = p;
        __syncthreads();

        float pre = running_T;
        for (int w2 = 0; w2 < wid; ++w2) pre *= s_wtot[w2];
        float chunk_prod = s_wtot[0] * s_wtot[1] * s_wtot[2] * s_wtot[3];
        float T   = pre * p;                    // inclusive transmittance
        float wgt = act ? alpha * T : 0.0f;
        const bool live = act && (T > EPS);

        // ---- rare fallback: live non-spec samples gather their half ----
        if (live && !spec) {
            if (h == 0) {
                #pragma unroll
                for (int i = 1; i < 5; ++i)
                    part[i] = w * SGLV[(size_t)chA[i] * CS + base];
            } else {
                #pragma unroll
                for (int i = 0; i < 6; ++i)
                    part[i] = w * SGLV[(size_t)chB[i] * CS + base];
            }
        }

        // ---- accumulate (chunk-0 threads exact regardless of live) ----
        #pragma unroll
        for (int i = 0; i < 6; ++i)
            accL[i] += wgt * part[i];

        running_T *= chunk_prod;
        __syncthreads();                        // protect s_wtot next iter
        if (running_T <= EPS) break;            // block-uniform exit
    }

    // ---- masked butterfly: reduce over corner+sg bits, NOT the h bit ----
    #pragma unroll
    for (int i = 0; i < 6; ++i) {
        float val = accL[i];
        val += __shfl_xor(val, 1, 64);
        val += __shfl_xor(val, 2, 64);
        val += __shfl_xor(val, 4, 64);
        val += __shfl_xor(val, 16, 64);
        val += __shfl_xor(val, 32, 64);
        accL[i] = val;                          // lane 0 (h=0) / 8 (h=1)
    }
    if (lane == 0) {
        #pragma unroll
        for (int i = 0; i < 5; ++i) s_red[wid][chA[i]] = accL[i];
    }
    if (lane == 8) {
        #pragma unroll
        for (int i = 0; i < 6; ++i) s_red[wid][chB[i]] = accL[i];
    }
    __syncthreads();

    if (tid == 0) {
        float a[NCH];
        #pragma unroll
        for (int c = 0; c < NCH; ++c)
            a[c] = s_red[0][c] + s_red[1][c] + s_red[2][c] + s_red[3][c];
        float sdd = d[0] * a[8] + d[1] * a[9] + d[2] * a[10];
        float e = expf(a[7] * (sdd - 1.0f));
        int pix = v * RES_H + u;
        out[0 * RES_V * RES_H + pix] = a[0] + a[4] * e;
        out[1 * RES_V * RES_H + pix] = a[1] + a[5] * e;
        out[2 * RES_V * RES_H + pix] = a[2] + a[6] * e;
    }
}

extern "C" void kernel_launch(void* const* d_in, const int* in_sizes, int n_in,
                              void* d_out, int out_size, void* d_ws, size_t ws_size,
                              hipStream_t stream) {
    const float* origin = (const float*)d_in[0];
    const float* SGLV   = (const float*)d_in[1];
    const float* vrange = (const float*)d_in[2];
    float* out = (float*)d_out;

    sglv_render_kernel<<<dim3(RES_V * RES_H), dim3(BLK), 0, stream>>>(
        origin, SGLV, vrange, out);
}